// Round 9
// baseline (418.369 us; speedup 1.0000x reference)
//
#include <hip/hip_runtime.h>
#include <stdint.h>

#define S 2048
#define HID 3584
#define NH 16
#define NKV 8
#define DH 256
#define WINDOW 1024
#define SCALE 0.0625f
#define CAP 50.0f

typedef short s16x8 __attribute__((ext_vector_type(8)));
typedef float f32x4 __attribute__((ext_vector_type(4)));

__device__ __forceinline__ short f2bf(float f) {
  union { float f; uint32_t u; } c; c.f = f;
  uint32_t u = c.u;
  uint32_t r = (u + 0x7FFFu + ((u >> 16) & 1u)) >> 16;
  return (short)r;
}
__device__ __forceinline__ float bf2f(short s) {
  union { uint32_t u; float f; } c;
  c.u = ((uint32_t)(uint16_t)s) << 16;
  return c.f;
}
__device__ __forceinline__ void gll16(const void* g, void* l) {
  __builtin_amdgcn_global_load_lds((const __attribute__((address_space(1))) void*)g,
                                   (__attribute__((address_space(3))) void*)l, 16, 0, 0);
}
#define BAR() asm volatile("s_barrier" ::: "memory")
#define VW6() asm volatile("s_waitcnt vmcnt(6)" ::: "memory")

// ---------------- RoPE table ----------------
__global__ void rope_table_kernel(float2* __restrict__ tbl) {
  int idx = blockIdx.x * 256 + threadIdx.x;
  int s = idx >> 7, i = idx & 127;
  float inv = __expf(-(float)i * (9.210340371976184f / 128.0f));
  float fr = (float)s * inv;
  tbl[idx] = make_float2(cosf(fr), sinf(fr));
}

// ---------------- hs fp32 -> bf16 ----------------
__global__ void conv_hs_kernel(const float* __restrict__ src, short* __restrict__ dst) {
  int gid = blockIdx.x * 256 + threadIdx.x;
  float4 a = *(const float4*)&src[(size_t)gid * 8];
  float4 b = *(const float4*)&src[(size_t)gid * 8 + 4];
  s16x8 o;
  o[0] = f2bf(a.x); o[1] = f2bf(a.y); o[2] = f2bf(a.z); o[3] = f2bf(a.w);
  o[4] = f2bf(b.x); o[5] = f2bf(b.y); o[6] = f2bf(b.z); o[7] = f2bf(b.w);
  *(s16x8*)&dst[(size_t)gid * 8] = o;
}

// ---------------- W fp32 [K][N] -> bf16 [N][K] (transpose+convert) --------
__global__ __launch_bounds__(256)
void transpose_kernel(const float* __restrict__ src, short* __restrict__ dst,
                      int K, int N)
{
  __shared__ __align__(16) short t[64][76];
  int ntn = N >> 6;
  int tn = blockIdx.x % ntn, tk = blockIdx.x / ntn;
  int tid = threadIdx.x;
  int c = tid & 63, rg = tid >> 6;
  #pragma unroll
  for (int i = 0; i < 4; ++i) {
    int r0 = i * 16 + rg * 4;
    short tmp[4];
    #pragma unroll
    for (int j = 0; j < 4; ++j)
      tmp[j] = f2bf(src[(size_t)(tk * 64 + r0 + j) * N + tn * 64 + c]);
    *(short4*)&t[c][r0] = *(short4*)tmp;
  }
  __syncthreads();
  #pragma unroll
  for (int it = 0; it < 2; ++it) {
    int flat = it * 256 + tid;
    int n = flat >> 3, kc = flat & 7;
    *(s16x8*)&dst[(size_t)(tn * 64 + n) * K + tk * 64 + kc * 8] = *(s16x8*)&t[n][kc * 8];
  }
}

// ====== 8-phase 256xBN GEMM core with PIPELINED fragment reads =============
// Each phase: {stage gll16; [VW6 @ph4/8]; BAR; read NEXT phase's frags (C++,
// compiler emits counted lgkmcnt); sched_barrier; MFMA on frags read LAST
// phase; BAR}. LDS reads drain under the MFMA cluster.
template<int BN, int KS>
__device__ __forceinline__ void gemm_ph(const short* __restrict__ srcA,
                                        const short* __restrict__ srcB,
                                        int tid, int NT,
                                        f32x4 (&acc)[8][BN / 64])
{
  constexpr int NFP = BN / 128;          // n-frags per phase: 2 or 1
  constexpr int BTILE = BN * 64;
  __shared__ __align__(16) short Asb[2 * 16384];
  __shared__ __align__(16) short Bsb[2 * BTILE];
  const int wv = tid >> 6, lane = tid & 63;
  const int lr = lane & 15, lk = lane >> 4;
  const int wm_id = wv >> 2, wn_id = wv & 3;
  const int r7 = lr & 7;
  const int abase = (wm_id * 128 + lr) * 64 + ((lk ^ r7) * 8);
  const int bbase = (wn_id * (BN / 4) + lr) * 64 + ((lk ^ r7) * 8);

  s16x8 afA[4][2], afB[4][2];            // m-half frag sets (A0 / A1)
  s16x8 bf0[NFP][2], bf1[NFP][2];        // n-half frag sets (B0 / B1)

  auto stA = [&](int ts, int r, int b) {
    gll16(srcA + (size_t)ts * 64 + (size_t)(r * 64) * KS,
          Asb + b * 16384 + r * 4096 + wv * 512);
  };
  auto stB = [&](int ts, int q, int b) {
    gll16(srcB + (size_t)ts * 64 + (size_t)(q * 64) * KS,
          Bsb + b * BTILE + q * 4096 + wv * 512);
  };
  auto RDA = [&](s16x8 (&dst)[4][2], int mh, int b) {
    const short* A = Asb + b * 16384;
    #pragma unroll
    for (int mf = 0; mf < 4; ++mf)
      #pragma unroll
      for (int kh = 0; kh < 2; ++kh)
        dst[mf][kh] = *(const s16x8*)&A[(abase + (mh * 64 + mf * 16) * 64) ^ (kh * 32)];
  };
  auto RDB = [&](s16x8 (&dst)[NFP][2], int nh, int b) {
    const short* B = Bsb + b * BTILE;
    #pragma unroll
    for (int nf = 0; nf < NFP; ++nf)
      #pragma unroll
      for (int kh = 0; kh < 2; ++kh)
        dst[nf][kh] = *(const s16x8*)&B[(bbase + (nh * NFP + nf) * 16 * 64) ^ (kh * 32)];
  };
  auto MMA = [&](s16x8 (&fa)[4][2], s16x8 (&fb)[NFP][2], int mh, int nh) {
    __builtin_amdgcn_sched_barrier(0);
    __builtin_amdgcn_s_setprio(1);
    #pragma unroll
    for (int mf = 0; mf < 4; ++mf)
      #pragma unroll
      for (int nf = 0; nf < NFP; ++nf) {
        acc[mh * 4 + mf][nh * NFP + nf] =
          __builtin_amdgcn_mfma_f32_16x16x32_bf16(fa[mf][0], fb[nf][0],
                                                  acc[mh * 4 + mf][nh * NFP + nf], 0, 0, 0);
        acc[mh * 4 + mf][nh * NFP + nf] =
          __builtin_amdgcn_mfma_f32_16x16x32_bf16(fa[mf][1], fb[nf][1],
                                                  acc[mh * 4 + mf][nh * NFP + nf], 0, 0, 0);
      }
    __builtin_amdgcn_s_setprio(0);
  };

  // ---- prologue: tile0 full; tile1 A full + B q0,q1 ----
  #pragma unroll
  for (int r = 0; r < 4; ++r) stA(0, r, 0);
  #pragma unroll
  for (int q = 0; q < BN / 64; ++q) stB(0, q, 0);
  #pragma unroll
  for (int r = 0; r < 4; ++r) stA(1, r, 1);
  stB(1, 0, 1); stB(1, 1, 1);
  asm volatile("s_waitcnt vmcnt(0)" ::: "memory");
  BAR();
  RDA(afA, 0, 0); RDB(bf0, 0, 0);        // pre-read ph1 frags (tile0, buf0)

  const int NI = NT / 2;
  for (int i = 0; i < NI; ++i) {
    const int T = 2 * i;
    const int t2 = (T + 2 < NT) ? T + 2 : NT - 2;
    const int t3 = (T + 3 < NT) ? T + 3 : NT - 1;
    // ---- ph1: tile T (buf0), MMA(0,0); read B1(buf0) ----
    if constexpr (BN == 256) { stB(T + 1, 2, 1); stB(T + 1, 3, 1); }
    BAR();
    RDB(bf1, 1, 0);
    MMA(afA, bf0, 0, 0);
    BAR();
    // ---- ph2: MMA(0,1); read A1(buf0) ----
    stA(t2, 0, 0); stA(t2, 2, 0);
    BAR();
    RDA(afB, 1, 0);
    MMA(afA, bf1, 0, 1);
    BAR();
    // ---- ph3: MMA(1,0) ----
    stB(t2, 0, 0); stB(t2, 1, 0);
    BAR();
    MMA(afB, bf0, 1, 0);
    BAR();
    // ---- ph4: MMA(1,1); read A0,B0 of tile T+1 (buf1) ----
    stA(t2, 1, 0); stA(t2, 3, 0);
    VW6();
    BAR();
    RDA(afA, 0, 1); RDB(bf0, 0, 1);
    MMA(afB, bf1, 1, 1);
    BAR();
    // ---- ph5: tile T+1 (buf1), MMA(0,0); read B1(buf1) ----
    if constexpr (BN == 256) { stB(t2, 2, 0); stB(t2, 3, 0); }
    BAR();
    RDB(bf1, 1, 1);
    MMA(afA, bf0, 0, 0);
    BAR();
    // ---- ph6: MMA(0,1); read A1(buf1) ----
    stA(t3, 0, 1); stA(t3, 2, 1);
    BAR();
    RDA(afB, 1, 1);
    MMA(afA, bf1, 0, 1);
    BAR();
    // ---- ph7: MMA(1,0) ----
    stB(t3, 0, 1); stB(t3, 1, 1);
    BAR();
    MMA(afB, bf0, 1, 0);
    BAR();
    // ---- ph8: MMA(1,1); read A0,B0 of tile T+2 (buf0) ----
    stA(t3, 1, 1); stA(t3, 3, 1);
    VW6();
    BAR();
    RDA(afA, 0, 0); RDB(bf0, 0, 0);
    MMA(afB, bf1, 1, 1);
    BAR();
  }
  asm volatile("s_waitcnt vmcnt(0)" ::: "memory");
}

// ---------------- Fused QKV GEMM (256^2) ----------------
__global__ __launch_bounds__(512, 2)
void qkv_gemm8_kernel(const short* __restrict__ hsb, const short* __restrict__ Wt,
                      short* __restrict__ qb, short* __restrict__ kbuf,
                      short* __restrict__ vtb)
{
  int bid = blockIdx.x;
  int swz = (bid & 7) * 32 + (bid >> 3);
  int bm = swz >> 5, bn = swz & 31;
  int m0 = bm * 256, n0 = bn * 256;
  int tid = threadIdx.x;
  int row8 = tid >> 3;
  int colsw = ((tid & 7) ^ (row8 & 7)) * 8;
  const short* srcA = hsb + (size_t)(m0 + row8) * HID + colsw;
  const short* srcB = Wt + (size_t)(n0 + row8) * HID + colsw;
  f32x4 acc[8][4] = {};
  gemm_ph<256, HID>(srcA, srcB, tid, HID / 64, acc);

  int wv = tid >> 6, lane = tid & 63;
  int lr = lane & 15, lk = lane >> 4;
  int wm = (wv >> 2) * 128, wn = (wv & 3) * 64;
  int region = (n0 < 4096) ? 0 : ((n0 < 6144) ? 1 : 2);
  #pragma unroll
  for (int m = 0; m < 8; ++m) {
    int srow_b = m0 + wm + m * 16 + lk * 4;
    #pragma unroll
    for (int n = 0; n < 4; ++n) {
      int ncol = n0 + wn + n * 16 + lr;
      #pragma unroll
      for (int r = 0; r < 4; ++r) {
        int srow = srow_b + r;
        short bv = f2bf(acc[m][n][r]);
        if (region == 0) {
          int h = ncol >> 8, d = ncol & 255;
          qb[((size_t)h * S + srow) * DH + d] = bv;
        } else if (region == 1) {
          int c = ncol - 4096; int kv = c >> 8, d = c & 255;
          kbuf[((size_t)kv * S + srow) * DH + d] = bv;
        } else {
          int c = ncol - 6144; int kv = c >> 8, d = c & 255;
          vtb[((size_t)kv * DH + d) * S + srow] = bv;
        }
      }
    }
  }
}

// ---------------- Output GEMM (256x128) ----------------
__global__ __launch_bounds__(512, 2)
void out_gemm8_kernel(const short* __restrict__ attnb, const short* __restrict__ WtO,
                      float* __restrict__ out)
{
  int bid = blockIdx.x;
  int swz = (bid & 7) * 28 + (bid >> 3);
  int bm = swz / 28, bn = swz % 28;
  int m0 = bm * 256, n0 = bn * 128;
  int tid = threadIdx.x;
  int row8 = tid >> 3;
  int colsw = ((tid & 7) ^ (row8 & 7)) * 8;
  const short* srcA = attnb + (size_t)(m0 + row8) * 4096 + colsw;
  const short* srcB = WtO + (size_t)(n0 + row8) * 4096 + colsw;
  f32x4 acc[8][2] = {};
  gemm_ph<128, 4096>(srcA, srcB, tid, 4096 / 64, acc);

  int wv = tid >> 6, lane = tid & 63;
  int lr = lane & 15, lk = lane >> 4;
  int wm = (wv >> 2) * 128, wn = (wv & 3) * 32;
  #pragma unroll
  for (int m = 0; m < 8; ++m) {
    int srow_b = m0 + wm + m * 16 + lk * 4;
    #pragma unroll
    for (int n = 0; n < 2; ++n) {
      int ncol = n0 + wn + n * 16 + lr;
      #pragma unroll
      for (int r = 0; r < 4; ++r)
        out[(size_t)(srow_b + r) * HID + ncol] = acc[m][n][r];
    }
  }
}

// ---------------- RoPE (NeoX, in place on q and k) ----------------
__global__ void rope_kernel(short* __restrict__ qb, short* __restrict__ kbuf,
                            const float2* __restrict__ tbl)
{
  int gid = blockIdx.x * 256 + threadIdx.x;
  int row = gid >> 4, ch = gid & 15;
  short* base = (row < NH * S) ? (qb + (size_t)row * DH)
                               : (kbuf + (size_t)(row - NH * S) * DH);
  int s = row & (S - 1);
  int i0 = ch * 8;
  s16x8 x1 = *(s16x8*)(base + i0);
  s16x8 x2 = *(s16x8*)(base + 128 + i0);
  s16x8 y1, y2;
  #pragma unroll
  for (int j = 0; j < 8; ++j) {
    float2 cs = tbl[s * 128 + i0 + j];
    float a = bf2f(x1[j]), b = bf2f(x2[j]);
    y1[j] = f2bf(a * cs.x - b * cs.y);
    y2[j] = f2bf(b * cs.x + a * cs.y);
  }
  *(s16x8*)(base + i0) = y1;
  *(s16x8*)(base + 128 + i0) = y2;
}

// ---------------- Attention v4 (unchanged from R8) ----------------
__global__ __launch_bounds__(256)
void attn_kernel(const short* __restrict__ qb, const short* __restrict__ kbuf,
                 const short* __restrict__ vtb, short* __restrict__ attnb)
{
  __shared__ __align__(16) short Klds[64][256];   // swizzled: chunk ^= row&7
  __shared__ __align__(16) short Vlds[256][72];   // [d][k], pad 72
  __shared__ __align__(16) short Plds[4][16][76]; // per-wave P, pad 76
  int bid = blockIdx.x;
  int qt = bid >> 4, h = bid & 15;
  int kv = h >> 1;
  int q0 = qt * 64;
  int tid = threadIdx.x, w = tid >> 6, lane = tid & 63;
  int lr = lane & 15, lk = lane >> 4;
  int qrow_base = q0 + w * 16;
  s16x8 qf[8];
  const short* qrow = qb + ((size_t)h * S + (qrow_base + lr)) * DH;
  #pragma unroll
  for (int kb = 0; kb < 8; ++kb)
    qf[kb] = *(const s16x8*)(qrow + kb * 32 + lk * 8);
  f32x4 acc_o[16] = {};
  float l_r[4] = {0.0f, 0.0f, 0.0f, 0.0f};
  int tlo = (q0 >= WINDOW - 1) ? ((q0 - (WINDOW - 1)) >> 6) : 0;
  int thi = q0 >> 6;
  const short* kbase = kbuf + (size_t)kv * S * DH;
  const short* vbase = vtb + (size_t)kv * DH * S;

  s16x8 kpf[8], vpf[8];
  auto loadRegs = [&](int t) {
    int k0 = t * 64;
    #pragma unroll
    for (int it = 0; it < 8; ++it) {
      int flat = it * 256 + tid;
      int r = flat >> 5, cg = flat & 31;
      kpf[it] = *(const s16x8*)(kbase + (size_t)(k0 + r) * DH + cg * 8);
    }
    #pragma unroll
    for (int it = 0; it < 8; ++it) {
      int flat = it * 256 + tid;
      int r = flat >> 3, cg = flat & 7;
      vpf[it] = *(const s16x8*)(vbase + (size_t)r * S + k0 + cg * 8);
    }
  };
  auto writeLds = [&]() {
    #pragma unroll
    for (int it = 0; it < 8; ++it) {
      int flat = it * 256 + tid;
      int r = flat >> 5, cg = flat & 31;
      *(s16x8*)&Klds[r][(cg ^ (r & 7)) * 8] = kpf[it];
    }
    #pragma unroll
    for (int it = 0; it < 8; ++it) {
      int flat = it * 256 + tid;
      int r = flat >> 3, cg = flat & 7;
      *(s16x8*)&Vlds[r][cg * 8] = vpf[it];
    }
  };

  loadRegs(tlo);
  for (int t = tlo; t <= thi; ++t) {
    int k0 = t * 64;
    writeLds();
    __syncthreads();
    if (t < thi) loadRegs(t + 1);
    f32x4 sc4[4] = {};
    __builtin_amdgcn_s_setprio(1);
    #pragma unroll
    for (int kb = 0; kb < 8; ++kb)
      #pragma unroll
      for (int ni = 0; ni < 4; ++ni) {
        int row = ni * 16 + lr;
        s16x8 b = *(const s16x8*)&Klds[row][(((kb << 2) | lk) ^ (row & 7)) * 8];
        sc4[ni] = __builtin_amdgcn_mfma_f32_16x16x32_bf16(qf[kb], b, sc4[ni], 0, 0, 0);
      }
    __builtin_amdgcn_s_setprio(0);
    bool interior = (k0 + 63 <= qrow_base) && (qrow_base + 15 - k0 < WINDOW);
    #pragma unroll
    for (int ni = 0; ni < 4; ++ni)
      #pragma unroll
      for (int r = 0; r < 4; ++r) {
        float raw = sc4[ni][r];
        float u = fabsf(raw) * (2.0f * SCALE / CAP);
        float e = __expf(-u);
        float th = (1.0f - e) / (1.0f + e);
        float z = CAP * copysignf(th, raw) - CAP;
        if (!interior) {
          int qg = qrow_base + lk * 4 + r;
          int kg = k0 + ni * 16 + lr;
          bool valid = (kg <= qg) && (qg - kg < WINDOW);
          z = valid ? z : -1e30f;
        }
        float p = __expf(z);
        sc4[ni][r] = p;
        l_r[r] += p;
      }
    #pragma unroll
    for (int ni = 0; ni < 4; ++ni)
      #pragma unroll
      for (int r = 0; r < 4; ++r)
        Plds[w][lk * 4 + r][ni * 16 + lr] = f2bf(sc4[ni][r]);
    s16x8 pa0 = *(const s16x8*)&Plds[w][lr][lk * 8];
    s16x8 pa1 = *(const s16x8*)&Plds[w][lr][32 + lk * 8];
    __builtin_amdgcn_s_setprio(1);
    #pragma unroll
    for (int df = 0; df < 16; ++df) {
      s16x8 b0 = *(const s16x8*)&Vlds[df * 16 + lr][lk * 8];
      s16x8 b1 = *(const s16x8*)&Vlds[df * 16 + lr][32 + lk * 8];
      acc_o[df] = __builtin_amdgcn_mfma_f32_16x16x32_bf16(pa0, b0, acc_o[df], 0, 0, 0);
      acc_o[df] = __builtin_amdgcn_mfma_f32_16x16x32_bf16(pa1, b1, acc_o[df], 0, 0, 0);
    }
    __builtin_amdgcn_s_setprio(0);
    __syncthreads();
  }
  #pragma unroll
  for (int r = 0; r < 4; ++r) {
    float lsum = l_r[r];
    #pragma unroll
    for (int off = 1; off < 16; off <<= 1)
      lsum += __shfl_xor(lsum, off, 64);
    float inv = 1.0f / lsum;
    int srow = qrow_base + lk * 4 + r;
    #pragma unroll
    for (int df = 0; df < 16; ++df)
      attnb[(size_t)srow * (NH * DH) + h * DH + df * 16 + lr] = f2bf(acc_o[df][r] * inv);
  }
}

extern "C" void kernel_launch(void* const* d_in, const int* in_sizes, int n_in,
                              void* d_out, int out_size, void* d_ws, size_t ws_size,
                              hipStream_t stream) {
  const float* hs = (const float*)d_in[0];
  const float* Wq = (const float*)d_in[2];
  const float* Wk = (const float*)d_in[3];
  const float* Wv = (const float*)d_in[4];
  const float* Wo = (const float*)d_in[5];
  float* out = (float*)d_out;
  char* ws = (char*)d_ws;
  size_t off = 0;
  float2* tbl  = (float2*)(ws + off); off += 2097152;
  short* qb    = (short*)(ws + off);  off += 16777216;           // q  [H][S][D]
  short* kbuf  = (short*)(ws + off);  off += 8388608;            // k  [KV][S][D]
  short* vtb   = (short*)(ws + off);  off += 8388608;            // vT [KV][D][S]
  short* attnb = (short*)(ws + off);  off += 16777216;           // attn [S][4096]
  short* hsb   = (short*)(ws + off);  off += 14680064;           // hs bf16
  short* Wt    = (short*)(ws + off);  off += 58720256;           // [8192][3584]
  short* WtO   = (short*)(ws + off);  off += 29360128;           // [3584][4096]

  hipLaunchKernelGGL(rope_table_kernel, dim3(1024), dim3(256), 0, stream, tbl);
  hipLaunchKernelGGL(conv_hs_kernel, dim3(3584), dim3(256), 0, stream, hs, hsb);
  hipLaunchKernelGGL(transpose_kernel, dim3(64 * 56), dim3(256), 0, stream,
                     Wq, Wt, HID, 4096);
  hipLaunchKernelGGL(transpose_kernel, dim3(32 * 56), dim3(256), 0, stream,
                     Wk, Wt + (size_t)4096 * HID, HID, 2048);
  hipLaunchKernelGGL(transpose_kernel, dim3(32 * 56), dim3(256), 0, stream,
                     Wv, Wt + (size_t)6144 * HID, HID, 2048);
  hipLaunchKernelGGL(transpose_kernel, dim3(56 * 64), dim3(256), 0, stream,
                     Wo, WtO, 4096, HID);
  hipLaunchKernelGGL(qkv_gemm8_kernel, dim3(256), dim3(512), 0, stream,
                     hsb, Wt, qb, kbuf, vtb);
  hipLaunchKernelGGL(rope_kernel, dim3(3072), dim3(256), 0, stream, qb, kbuf, tbl);
  hipLaunchKernelGGL(attn_kernel, dim3(512), dim3(256), 0, stream,
                     qb, kbuf, vtb, attnb);
  hipLaunchKernelGGL(out_gemm8_kernel, dim3(224), dim3(512), 0, stream,
                     attnb, WtO, out);
}

// Round 10
// 405.280 us; speedup vs baseline: 1.0323x; 1.0323x over previous
//
#include <hip/hip_runtime.h>
#include <stdint.h>

#define S 2048
#define HID 3584
#define NH 16
#define NKV 8
#define DH 256
#define WINDOW 1024
#define SCALE 0.0625f
#define CAP 50.0f

typedef short s16x8 __attribute__((ext_vector_type(8)));
typedef float f32x4 __attribute__((ext_vector_type(4)));

__device__ __forceinline__ short f2bf(float f) {
  union { float f; uint32_t u; } c; c.f = f;
  uint32_t u = c.u;
  uint32_t r = (u + 0x7FFFu + ((u >> 16) & 1u)) >> 16;
  return (short)r;
}
__device__ __forceinline__ float bf2f(short s) {
  union { uint32_t u; float f; } c;
  c.u = ((uint32_t)(uint16_t)s) << 16;
  return c.f;
}
__device__ __forceinline__ void gll16(const void* g, void* l) {
  __builtin_amdgcn_global_load_lds((const __attribute__((address_space(1))) void*)g,
                                   (__attribute__((address_space(3))) void*)l, 16, 0, 0);
}
#define BAR() asm volatile("s_barrier" ::: "memory")
#define VW6() asm volatile("s_waitcnt vmcnt(6)" ::: "memory")

// ---------------- RoPE table ----------------
__global__ void rope_table_kernel(float2* __restrict__ tbl) {
  int idx = blockIdx.x * 256 + threadIdx.x;
  int s = idx >> 7, i = idx & 127;
  float inv = __expf(-(float)i * (9.210340371976184f / 128.0f));
  float fr = (float)s * inv;
  tbl[idx] = make_float2(cosf(fr), sinf(fr));
}

// ---------------- hs fp32 -> bf16 ----------------
__global__ void conv_hs_kernel(const float* __restrict__ src, short* __restrict__ dst) {
  int gid = blockIdx.x * 256 + threadIdx.x;
  float4 a = *(const float4*)&src[(size_t)gid * 8];
  float4 b = *(const float4*)&src[(size_t)gid * 8 + 4];
  s16x8 o;
  o[0] = f2bf(a.x); o[1] = f2bf(a.y); o[2] = f2bf(a.z); o[3] = f2bf(a.w);
  o[4] = f2bf(b.x); o[5] = f2bf(b.y); o[6] = f2bf(b.z); o[7] = f2bf(b.w);
  *(s16x8*)&dst[(size_t)gid * 8] = o;
}

// ---------------- W fp32 [K][N] -> bf16 [N][K] (transpose+convert) --------
__global__ __launch_bounds__(256)
void transpose_kernel(const float* __restrict__ src, short* __restrict__ dst,
                      int K, int N)
{
  __shared__ __align__(16) short t[64][76];
  int ntn = N >> 6;
  int tn = blockIdx.x % ntn, tk = blockIdx.x / ntn;
  int tid = threadIdx.x;
  int c = tid & 63, rg = tid >> 6;
  #pragma unroll
  for (int i = 0; i < 4; ++i) {
    int r0 = i * 16 + rg * 4;
    short tmp[4];
    #pragma unroll
    for (int j = 0; j < 4; ++j)
      tmp[j] = f2bf(src[(size_t)(tk * 64 + r0 + j) * N + tn * 64 + c]);
    *(short4*)&t[c][r0] = *(short4*)tmp;
  }
  __syncthreads();
  #pragma unroll
  for (int it = 0; it < 2; ++it) {
    int flat = it * 256 + tid;
    int n = flat >> 3, kc = flat & 7;
    *(s16x8*)&dst[(size_t)(tn * 64 + n) * K + tk * 64 + kc * 8] = *(s16x8*)&t[n][kc * 8];
  }
}

// ====== m201-style 8-phase 256xBN GEMM core, BK=64, 512 thr (R8 version) ===
template<int BN, int KS>
__device__ __forceinline__ void gemm_ph(const short* __restrict__ srcA,
                                        const short* __restrict__ srcB,
                                        int tid, int NT,
                                        f32x4 (&acc)[8][BN / 64])
{
  constexpr int NFP = BN / 128;          // n-frags per phase: 2 or 1
  constexpr int BTILE = BN * 64;
  __shared__ __align__(16) short Asb[2 * 16384];
  __shared__ __align__(16) short Bsb[2 * BTILE];
  const int wv = tid >> 6, lane = tid & 63;
  const int lr = lane & 15, lk = lane >> 4;
  const int wm_id = wv >> 2, wn_id = wv & 3;
  const int r7 = lr & 7;
  const int abase = (wm_id * 128 + lr) * 64 + ((lk ^ r7) * 8);
  const int bbase = (wn_id * (BN / 4) + lr) * 64 + ((lk ^ r7) * 8);

  s16x8 af[4][2];            // current m-half frags
  s16x8 bfr[2][NFP][2];      // both n-half frags

  auto stA = [&](int ts, int r, int b) {
    gll16(srcA + (size_t)ts * 64 + (size_t)(r * 64) * KS,
          Asb + b * 16384 + r * 4096 + wv * 512);
  };
  auto stB = [&](int ts, int q, int b) {
    gll16(srcB + (size_t)ts * 64 + (size_t)(q * 64) * KS,
          Bsb + b * BTILE + q * 4096 + wv * 512);
  };
  auto LDA = [&](int mh, int b) {
    const short* A = Asb + b * 16384;
    #pragma unroll
    for (int mf = 0; mf < 4; ++mf)
      #pragma unroll
      for (int kh = 0; kh < 2; ++kh)
        af[mf][kh] = *(const s16x8*)&A[(abase + (mh * 64 + mf * 16) * 64) ^ (kh * 32)];
  };
  auto LDB = [&](int nh, int b) {
    const short* B = Bsb + b * BTILE;
    #pragma unroll
    for (int nf = 0; nf < NFP; ++nf)
      #pragma unroll
      for (int kh = 0; kh < 2; ++kh)
        bfr[nh][nf][kh] = *(const s16x8*)&B[(bbase + (nh * NFP + nf) * 16 * 64) ^ (kh * 32)];
  };
  auto MMA = [&](int mh, int nh) {
    asm volatile("s_waitcnt lgkmcnt(0)" ::: "memory");
    __builtin_amdgcn_sched_barrier(0);
    __builtin_amdgcn_s_setprio(1);
    #pragma unroll
    for (int mf = 0; mf < 4; ++mf)
      #pragma unroll
      for (int nf = 0; nf < NFP; ++nf) {
        acc[mh * 4 + mf][nh * NFP + nf] =
          __builtin_amdgcn_mfma_f32_16x16x32_bf16(af[mf][0], bfr[nh][nf][0],
                                                  acc[mh * 4 + mf][nh * NFP + nf], 0, 0, 0);
        acc[mh * 4 + mf][nh * NFP + nf] =
          __builtin_amdgcn_mfma_f32_16x16x32_bf16(af[mf][1], bfr[nh][nf][1],
                                                  acc[mh * 4 + mf][nh * NFP + nf], 0, 0, 0);
      }
    __builtin_amdgcn_s_setprio(0);
  };

  #pragma unroll
  for (int r = 0; r < 4; ++r) stA(0, r, 0);
  #pragma unroll
  for (int q = 0; q < BN / 64; ++q) stB(0, q, 0);
  #pragma unroll
  for (int r = 0; r < 4; ++r) stA(1, r, 1);
  stB(1, 0, 1); stB(1, 1, 1);
  asm volatile("s_waitcnt vmcnt(0)" ::: "memory");
  BAR();

  const int NI = NT / 2;
  for (int i = 0; i < NI; ++i) {
    const int T = 2 * i;
    const int t2 = (T + 2 < NT) ? T + 2 : NT - 2;
    const int t3 = (T + 3 < NT) ? T + 3 : NT - 1;
    LDA(0, 0); LDB(0, 0);
    if constexpr (BN == 256) { stB(T + 1, 2, 1); stB(T + 1, 3, 1); }
    BAR(); MMA(0, 0); BAR();
    LDB(1, 0);
    stA(t2, 0, 0); stA(t2, 2, 0);
    BAR(); MMA(0, 1); BAR();
    LDA(1, 0);
    stB(t2, 0, 0); stB(t2, 1, 0);
    BAR(); MMA(1, 0); BAR();
    stA(t2, 1, 0); stA(t2, 3, 0);
    VW6();
    BAR(); MMA(1, 1); BAR();
    LDA(0, 1); LDB(0, 1);
    if constexpr (BN == 256) { stB(t2, 2, 0); stB(t2, 3, 0); }
    BAR(); MMA(0, 0); BAR();
    LDB(1, 1);
    stA(t3, 0, 1); stA(t3, 2, 1);
    BAR(); MMA(0, 1); BAR();
    LDA(1, 1);
    stB(t3, 0, 1); stB(t3, 1, 1);
    BAR(); MMA(1, 0); BAR();
    stA(t3, 1, 1); stA(t3, 3, 1);
    VW6();
    BAR(); MMA(1, 1); BAR();
  }
  asm volatile("s_waitcnt vmcnt(0)" ::: "memory");
}

// ---------------- Fused QKV GEMM (256^2) ----------------
__global__ __launch_bounds__(512, 2)
void qkv_gemm8_kernel(const short* __restrict__ hsb, const short* __restrict__ Wt,
                      short* __restrict__ qb, short* __restrict__ kbuf,
                      short* __restrict__ vtb)
{
  int bid = blockIdx.x;
  int swz = (bid & 7) * 32 + (bid >> 3);
  int bm = swz >> 5, bn = swz & 31;
  int m0 = bm * 256, n0 = bn * 256;
  int tid = threadIdx.x;
  int row8 = tid >> 3;
  int colsw = ((tid & 7) ^ (row8 & 7)) * 8;
  const short* srcA = hsb + (size_t)(m0 + row8) * HID + colsw;
  const short* srcB = Wt + (size_t)(n0 + row8) * HID + colsw;
  f32x4 acc[8][4] = {};
  gemm_ph<256, HID>(srcA, srcB, tid, HID / 64, acc);

  int wv = tid >> 6, lane = tid & 63;
  int lr = lane & 15, lk = lane >> 4;
  int wm = (wv >> 2) * 128, wn = (wv & 3) * 64;
  int region = (n0 < 4096) ? 0 : ((n0 < 6144) ? 1 : 2);
  #pragma unroll
  for (int m = 0; m < 8; ++m) {
    int srow_b = m0 + wm + m * 16 + lk * 4;
    #pragma unroll
    for (int n = 0; n < 4; ++n) {
      int ncol = n0 + wn + n * 16 + lr;
      #pragma unroll
      for (int r = 0; r < 4; ++r) {
        int srow = srow_b + r;
        short bv = f2bf(acc[m][n][r]);
        if (region == 0) {
          int h = ncol >> 8, d = ncol & 255;
          qb[((size_t)h * S + srow) * DH + d] = bv;
        } else if (region == 1) {
          int c = ncol - 4096; int kv = c >> 8, d = c & 255;
          kbuf[((size_t)kv * S + srow) * DH + d] = bv;
        } else {
          int c = ncol - 6144; int kv = c >> 8, d = c & 255;
          vtb[((size_t)kv * DH + d) * S + srow] = bv;
        }
      }
    }
  }
}

// ---------------- Output GEMM (256x128) ----------------
__global__ __launch_bounds__(512, 2)
void out_gemm8_kernel(const short* __restrict__ attnb, const short* __restrict__ WtO,
                      float* __restrict__ out)
{
  int bid = blockIdx.x;
  int swz = (bid & 7) * 28 + (bid >> 3);
  int bm = swz / 28, bn = swz % 28;
  int m0 = bm * 256, n0 = bn * 128;
  int tid = threadIdx.x;
  int row8 = tid >> 3;
  int colsw = ((tid & 7) ^ (row8 & 7)) * 8;
  const short* srcA = attnb + (size_t)(m0 + row8) * 4096 + colsw;
  const short* srcB = WtO + (size_t)(n0 + row8) * 4096 + colsw;
  f32x4 acc[8][2] = {};
  gemm_ph<128, 4096>(srcA, srcB, tid, 4096 / 64, acc);

  int wv = tid >> 6, lane = tid & 63;
  int lr = lane & 15, lk = lane >> 4;
  int wm = (wv >> 2) * 128, wn = (wv & 3) * 32;
  #pragma unroll
  for (int m = 0; m < 8; ++m) {
    int srow_b = m0 + wm + m * 16 + lk * 4;
    #pragma unroll
    for (int n = 0; n < 2; ++n) {
      int ncol = n0 + wn + n * 16 + lr;
      #pragma unroll
      for (int r = 0; r < 4; ++r)
        out[(size_t)(srow_b + r) * HID + ncol] = acc[m][n][r];
    }
  }
}

// ---------------- RoPE (NeoX, in place on q and k) ----------------
__global__ void rope_kernel(short* __restrict__ qb, short* __restrict__ kbuf,
                            const float2* __restrict__ tbl)
{
  int gid = blockIdx.x * 256 + threadIdx.x;
  int row = gid >> 4, ch = gid & 15;
  short* base = (row < NH * S) ? (qb + (size_t)row * DH)
                               : (kbuf + (size_t)(row - NH * S) * DH);
  int s = row & (S - 1);
  int i0 = ch * 8;
  s16x8 x1 = *(s16x8*)(base + i0);
  s16x8 x2 = *(s16x8*)(base + 128 + i0);
  s16x8 y1, y2;
  #pragma unroll
  for (int j = 0; j < 8; ++j) {
    float2 cs = tbl[s * 128 + i0 + j];
    float a = bf2f(x1[j]), b = bf2f(x2[j]);
    y1[j] = f2bf(a * cs.x - b * cs.y);
    y2[j] = f2bf(b * cs.x + a * cs.y);
  }
  *(s16x8*)(base + i0) = y1;
  *(s16x8*)(base + 128 + i0) = y2;
}

// ---------------- Attention v5: 8-wave two-group k-split ----------------
// Block = (h, qt), 512 threads. Group g = waves 4g..4g+3 processes k-tiles
// tlo+g, tlo+g+2, ... into its own K/V double-LDS. Fixed-shift softmax makes
// partials exactly additive -> combine via LDS at the end. qt-descending
// dispatch for LPT backfill. K and V LDS XOR-swizzled.
__global__ __launch_bounds__(512)
void attn_kernel(const short* __restrict__ qb, const short* __restrict__ kbuf,
                 const short* __restrict__ vtb, short* __restrict__ attnb)
{
  __shared__ __align__(16) short Klds[2][64][256];   // 64 KB
  __shared__ __align__(16) short Vlds[2][256][72];   // 73.7 KB
  __shared__ __align__(16) short Plds[8][16][72];    // 18.4 KB
  int bid = blockIdx.x;
  int qt = 31 - (bid >> 4), h = bid & 15;   // longest blocks first
  int kv = h >> 1;
  int q0 = qt * 64;
  int tid = threadIdx.x;
  int w = tid >> 6, lane = tid & 63;
  int g = w >> 2, wsub = w & 3;
  int gtid = tid & 255;                     // tid within group
  int lr = lane & 15, lk = lane >> 4;
  int qrow_base = q0 + wsub * 16;
  s16x8 qf[8];
  const short* qrow = qb + ((size_t)h * S + (qrow_base + lr)) * DH;
  #pragma unroll
  for (int kb = 0; kb < 8; ++kb)
    qf[kb] = *(const s16x8*)(qrow + kb * 32 + lk * 8);
  f32x4 acc_o[16] = {};
  float l_r[4] = {0.0f, 0.0f, 0.0f, 0.0f};
  int tlo = (q0 >= WINDOW - 1) ? ((q0 - (WINDOW - 1)) >> 6) : 0;
  int thi = q0 >> 6;
  const short* kbase = kbuf + (size_t)kv * S * DH;
  const short* vbase = vtb + (size_t)kv * DH * S;

  s16x8 kpf[8], vpf[8];
  auto loadRegs = [&](int t) {
    int k0 = t * 64;
    #pragma unroll
    for (int it = 0; it < 8; ++it) {
      int flat = it * 256 + gtid;
      int r = flat >> 5, cg = flat & 31;
      kpf[it] = *(const s16x8*)(kbase + (size_t)(k0 + r) * DH + cg * 8);
    }
    #pragma unroll
    for (int it = 0; it < 8; ++it) {
      int flat = it * 256 + gtid;
      int r = flat >> 3, cg = flat & 7;
      vpf[it] = *(const s16x8*)(vbase + (size_t)r * S + k0 + cg * 8);
    }
  };
  auto writeLds = [&]() {
    #pragma unroll
    for (int it = 0; it < 8; ++it) {
      int flat = it * 256 + gtid;
      int r = flat >> 5, cg = flat & 31;
      *(s16x8*)&Klds[g][r][(cg ^ (r & 7)) * 8] = kpf[it];
    }
    #pragma unroll
    for (int it = 0; it < 8; ++it) {
      int flat = it * 256 + gtid;
      int r = flat >> 3, cg = flat & 7;
      *(s16x8*)&Vlds[g][r][(cg ^ (r & 7)) * 8] = vpf[it];
    }
  };

  int tg0 = tlo + g;
  int n_all = thi - tlo + 1;
  int jmax = (n_all + 1) >> 1;
  if (tg0 <= thi) loadRegs(tg0);
  for (int j = 0; j < jmax; ++j) {
    int t = tg0 + 2 * j;
    bool active = (t <= thi);
    if (active) writeLds();
    __syncthreads();
    if (active && t + 2 <= thi) loadRegs(t + 2);
    if (active) {
      int k0 = t * 64;
      // QK^T (swizzled conflict-free reads)
      f32x4 sc4[4] = {};
      __builtin_amdgcn_s_setprio(1);
      #pragma unroll
      for (int kb = 0; kb < 8; ++kb)
        #pragma unroll
        for (int ni = 0; ni < 4; ++ni) {
          int row = ni * 16 + lr;
          s16x8 b = *(const s16x8*)&Klds[g][row][(((kb << 2) | lk) ^ (row & 7)) * 8];
          sc4[ni] = __builtin_amdgcn_mfma_f32_16x16x32_bf16(qf[kb], b, sc4[ni], 0, 0, 0);
        }
      __builtin_amdgcn_s_setprio(0);
      // softcap + mask + p = exp(capped - CAP)
      bool interior = (k0 + 63 <= qrow_base) && (qrow_base + 15 - k0 < WINDOW);
      #pragma unroll
      for (int ni = 0; ni < 4; ++ni)
        #pragma unroll
        for (int r = 0; r < 4; ++r) {
          float raw = sc4[ni][r];
          float u = fabsf(raw) * (2.0f * SCALE / CAP);
          float e = __expf(-u);
          float th = (1.0f - e) / (1.0f + e);
          float z = CAP * copysignf(th, raw) - CAP;
          if (!interior) {
            int qg = qrow_base + lk * 4 + r;
            int kg = k0 + ni * 16 + lr;
            bool valid = (kg <= qg) && (qg - kg < WINDOW);
            z = valid ? z : -1e30f;
          }
          float p = __expf(z);
          sc4[ni][r] = p;
          l_r[r] += p;
        }
      // P -> per-wave LDS, read back as A-frags (same wave: no barrier)
      #pragma unroll
      for (int ni = 0; ni < 4; ++ni)
        #pragma unroll
        for (int r = 0; r < 4; ++r)
          Plds[w][lk * 4 + r][ni * 16 + lr] = f2bf(sc4[ni][r]);
      s16x8 pa0 = *(const s16x8*)&Plds[w][lr][lk * 8];
      s16x8 pa1 = *(const s16x8*)&Plds[w][lr][32 + lk * 8];
      // PV from swizzled Vlds
      __builtin_amdgcn_s_setprio(1);
      #pragma unroll
      for (int df = 0; df < 16; ++df) {
        int row = df * 16 + lr;
        s16x8 b0 = *(const s16x8*)&Vlds[g][row][((lk ^ (row & 7)) * 8)];
        s16x8 b1 = *(const s16x8*)&Vlds[g][row][(((4 + lk) ^ (row & 7)) * 8)];
        acc_o[df] = __builtin_amdgcn_mfma_f32_16x16x32_bf16(pa0, b0, acc_o[df], 0, 0, 0);
        acc_o[df] = __builtin_amdgcn_mfma_f32_16x16x32_bf16(pa1, b1, acc_o[df], 0, 0, 0);
      }
      __builtin_amdgcn_s_setprio(0);
    }
    __syncthreads();
  }
  // lane-reduce l
  float lsum[4];
  #pragma unroll
  for (int r = 0; r < 4; ++r) {
    float v = l_r[r];
    #pragma unroll
    for (int off = 1; off < 16; off <<= 1)
      v += __shfl_xor(v, off, 64);
    lsum[r] = v;
  }
  // combine groups via LDS (K/V areas reused)
  float* comb = (float*)&Klds[0][0][0];   // [64][256] f32
  float* lcomb = (float*)&Vlds[0][0][0];  // [64] f32
  if (g == 1) {
    #pragma unroll
    for (int df = 0; df < 16; ++df)
      #pragma unroll
      for (int r = 0; r < 4; ++r)
        comb[(size_t)(wsub * 16 + lk * 4 + r) * 256 + df * 16 + lr] = acc_o[df][r];
    if (lr == 0)
      #pragma unroll
      for (int r = 0; r < 4; ++r)
        lcomb[wsub * 16 + lk * 4 + r] = lsum[r];
  }
  __syncthreads();
  if (g == 0) {
    #pragma unroll
    for (int r = 0; r < 4; ++r) {
      int rowi = wsub * 16 + lk * 4 + r;
      float lt = lsum[r] + lcomb[rowi];
      float inv = 1.0f / lt;
      int srow = q0 + rowi;
      #pragma unroll
      for (int df = 0; df < 16; ++df) {
        float o = acc_o[df][r] + comb[(size_t)rowi * 256 + df * 16 + lr];
        attnb[(size_t)srow * (NH * DH) + h * DH + df * 16 + lr] = f2bf(o * inv);
      }
    }
  }
}

extern "C" void kernel_launch(void* const* d_in, const int* in_sizes, int n_in,
                              void* d_out, int out_size, void* d_ws, size_t ws_size,
                              hipStream_t stream) {
  const float* hs = (const float*)d_in[0];
  const float* Wq = (const float*)d_in[2];
  const float* Wk = (const float*)d_in[3];
  const float* Wv = (const float*)d_in[4];
  const float* Wo = (const float*)d_in[5];
  float* out = (float*)d_out;
  char* ws = (char*)d_ws;
  size_t off = 0;
  float2* tbl  = (float2*)(ws + off); off += 2097152;
  short* qb    = (short*)(ws + off);  off += 16777216;           // q  [H][S][D]
  short* kbuf  = (short*)(ws + off);  off += 8388608;            // k  [KV][S][D]
  short* vtb   = (short*)(ws + off);  off += 8388608;            // vT [KV][D][S]
  short* attnb = (short*)(ws + off);  off += 16777216;           // attn [S][4096]
  short* hsb   = (short*)(ws + off);  off += 14680064;           // hs bf16
  short* Wt    = (short*)(ws + off);  off += 58720256;           // [8192][3584]
  short* WtO   = (short*)(ws + off);  off += 29360128;           // [3584][4096]

  hipLaunchKernelGGL(rope_table_kernel, dim3(1024), dim3(256), 0, stream, tbl);
  hipLaunchKernelGGL(conv_hs_kernel, dim3(3584), dim3(256), 0, stream, hs, hsb);
  hipLaunchKernelGGL(transpose_kernel, dim3(64 * 56), dim3(256), 0, stream,
                     Wq, Wt, HID, 4096);
  hipLaunchKernelGGL(transpose_kernel, dim3(32 * 56), dim3(256), 0, stream,
                     Wk, Wt + (size_t)4096 * HID, HID, 2048);
  hipLaunchKernelGGL(transpose_kernel, dim3(32 * 56), dim3(256), 0, stream,
                     Wv, Wt + (size_t)6144 * HID, HID, 2048);
  hipLaunchKernelGGL(transpose_kernel, dim3(56 * 64), dim3(256), 0, stream,
                     Wo, WtO, 4096, HID);
  hipLaunchKernelGGL(qkv_gemm8_kernel, dim3(256), dim3(512), 0, stream,
                     hsb, Wt, qb, kbuf, vtb);
  hipLaunchKernelGGL(rope_kernel, dim3(3072), dim3(256), 0, stream, qb, kbuf, tbl);
  hipLaunchKernelGGL(attn_kernel, dim3(512), dim3(512), 0, stream,
                     qb, kbuf, vtb, attnb);
  hipLaunchKernelGGL(out_gemm8_kernel, dim3(224), dim3(512), 0, stream,
                     attnb, WtO, out);
}

// Round 11
// 394.644 us; speedup vs baseline: 1.0601x; 1.0270x over previous
//
#include <hip/hip_runtime.h>
#include <stdint.h>

#define S 2048
#define HID 3584
#define NH 16
#define NKV 8
#define DH 256
#define WINDOW 1024
#define SCALE 0.0625f
#define CAP 50.0f

typedef short s16x8 __attribute__((ext_vector_type(8)));
typedef float f32x4 __attribute__((ext_vector_type(4)));

__device__ __forceinline__ short f2bf(float f) {
  union { float f; uint32_t u; } c; c.f = f;
  uint32_t u = c.u;
  uint32_t r = (u + 0x7FFFu + ((u >> 16) & 1u)) >> 16;
  return (short)r;
}
__device__ __forceinline__ float bf2f(short s) {
  union { uint32_t u; float f; } c;
  c.u = ((uint32_t)(uint16_t)s) << 16;
  return c.f;
}
__device__ __forceinline__ void gll16(const void* g, void* l) {
  __builtin_amdgcn_global_load_lds((const __attribute__((address_space(1))) void*)g,
                                   (__attribute__((address_space(3))) void*)l, 16, 0, 0);
}
#define BAR() asm volatile("s_barrier" ::: "memory")
#define VW6() asm volatile("s_waitcnt vmcnt(6)" ::: "memory")

// ---------------- RoPE table ----------------
__global__ void rope_table_kernel(float2* __restrict__ tbl) {
  int idx = blockIdx.x * 256 + threadIdx.x;
  int s = idx >> 7, i = idx & 127;
  float inv = __expf(-(float)i * (9.210340371976184f / 128.0f));
  float fr = (float)s * inv;
  tbl[idx] = make_float2(cosf(fr), sinf(fr));
}

// ---------------- hs fp32 -> bf16 ----------------
__global__ void conv_hs_kernel(const float* __restrict__ src, short* __restrict__ dst) {
  int gid = blockIdx.x * 256 + threadIdx.x;
  float4 a = *(const float4*)&src[(size_t)gid * 8];
  float4 b = *(const float4*)&src[(size_t)gid * 8 + 4];
  s16x8 o;
  o[0] = f2bf(a.x); o[1] = f2bf(a.y); o[2] = f2bf(a.z); o[3] = f2bf(a.w);
  o[4] = f2bf(b.x); o[5] = f2bf(b.y); o[6] = f2bf(b.z); o[7] = f2bf(b.w);
  *(s16x8*)&dst[(size_t)gid * 8] = o;
}

// ---------------- W fp32 [K][N] -> bf16 [N][K] (transpose+convert) --------
__global__ __launch_bounds__(256)
void transpose_kernel(const float* __restrict__ src, short* __restrict__ dst,
                      int K, int N)
{
  __shared__ __align__(16) short t[64][76];
  int ntn = N >> 6;
  int tn = blockIdx.x % ntn, tk = blockIdx.x / ntn;
  int tid = threadIdx.x;
  int c = tid & 63, rg = tid >> 6;
  #pragma unroll
  for (int i = 0; i < 4; ++i) {
    int r0 = i * 16 + rg * 4;
    short tmp[4];
    #pragma unroll
    for (int j = 0; j < 4; ++j)
      tmp[j] = f2bf(src[(size_t)(tk * 64 + r0 + j) * N + tn * 64 + c]);
    *(short4*)&t[c][r0] = *(short4*)tmp;
  }
  __syncthreads();
  #pragma unroll
  for (int it = 0; it < 2; ++it) {
    int flat = it * 256 + tid;
    int n = flat >> 3, kc = flat & 7;
    *(s16x8*)&dst[(size_t)(tn * 64 + n) * K + tk * 64 + kc * 8] = *(s16x8*)&t[n][kc * 8];
  }
}

// ====== m201-style 8-phase 256xBN GEMM core, BK=64, 512 thr (R8 version) ===
template<int BN, int KS>
__device__ __forceinline__ void gemm_ph(const short* __restrict__ srcA,
                                        const short* __restrict__ srcB,
                                        int tid, int NT,
                                        f32x4 (&acc)[8][BN / 64])
{
  constexpr int NFP = BN / 128;          // n-frags per phase: 2 or 1
  constexpr int BTILE = BN * 64;
  __shared__ __align__(16) short Asb[2 * 16384];
  __shared__ __align__(16) short Bsb[2 * BTILE];
  const int wv = tid >> 6, lane = tid & 63;
  const int lr = lane & 15, lk = lane >> 4;
  const int wm_id = wv >> 2, wn_id = wv & 3;
  const int r7 = lr & 7;
  const int abase = (wm_id * 128 + lr) * 64 + ((lk ^ r7) * 8);
  const int bbase = (wn_id * (BN / 4) + lr) * 64 + ((lk ^ r7) * 8);

  s16x8 af[4][2];            // current m-half frags
  s16x8 bfr[2][NFP][2];      // both n-half frags

  auto stA = [&](int ts, int r, int b) {
    gll16(srcA + (size_t)ts * 64 + (size_t)(r * 64) * KS,
          Asb + b * 16384 + r * 4096 + wv * 512);
  };
  auto stB = [&](int ts, int q, int b) {
    gll16(srcB + (size_t)ts * 64 + (size_t)(q * 64) * KS,
          Bsb + b * BTILE + q * 4096 + wv * 512);
  };
  auto LDA = [&](int mh, int b) {
    const short* A = Asb + b * 16384;
    #pragma unroll
    for (int mf = 0; mf < 4; ++mf)
      #pragma unroll
      for (int kh = 0; kh < 2; ++kh)
        af[mf][kh] = *(const s16x8*)&A[(abase + (mh * 64 + mf * 16) * 64) ^ (kh * 32)];
  };
  auto LDB = [&](int nh, int b) {
    const short* B = Bsb + b * BTILE;
    #pragma unroll
    for (int nf = 0; nf < NFP; ++nf)
      #pragma unroll
      for (int kh = 0; kh < 2; ++kh)
        bfr[nh][nf][kh] = *(const s16x8*)&B[(bbase + (nh * NFP + nf) * 16 * 64) ^ (kh * 32)];
  };
  auto MMA = [&](int mh, int nh) {
    asm volatile("s_waitcnt lgkmcnt(0)" ::: "memory");
    __builtin_amdgcn_sched_barrier(0);
    __builtin_amdgcn_s_setprio(1);
    #pragma unroll
    for (int mf = 0; mf < 4; ++mf)
      #pragma unroll
      for (int nf = 0; nf < NFP; ++nf) {
        acc[mh * 4 + mf][nh * NFP + nf] =
          __builtin_amdgcn_mfma_f32_16x16x32_bf16(af[mf][0], bfr[nh][nf][0],
                                                  acc[mh * 4 + mf][nh * NFP + nf], 0, 0, 0);
        acc[mh * 4 + mf][nh * NFP + nf] =
          __builtin_amdgcn_mfma_f32_16x16x32_bf16(af[mf][1], bfr[nh][nf][1],
                                                  acc[mh * 4 + mf][nh * NFP + nf], 0, 0, 0);
      }
    __builtin_amdgcn_s_setprio(0);
  };

  #pragma unroll
  for (int r = 0; r < 4; ++r) stA(0, r, 0);
  #pragma unroll
  for (int q = 0; q < BN / 64; ++q) stB(0, q, 0);
  #pragma unroll
  for (int r = 0; r < 4; ++r) stA(1, r, 1);
  stB(1, 0, 1); stB(1, 1, 1);
  asm volatile("s_waitcnt vmcnt(0)" ::: "memory");
  BAR();

  const int NI = NT / 2;
  for (int i = 0; i < NI; ++i) {
    const int T = 2 * i;
    const int t2 = (T + 2 < NT) ? T + 2 : NT - 2;
    const int t3 = (T + 3 < NT) ? T + 3 : NT - 1;
    LDA(0, 0); LDB(0, 0);
    if constexpr (BN == 256) { stB(T + 1, 2, 1); stB(T + 1, 3, 1); }
    BAR(); MMA(0, 0); BAR();
    LDB(1, 0);
    stA(t2, 0, 0); stA(t2, 2, 0);
    BAR(); MMA(0, 1); BAR();
    LDA(1, 0);
    stB(t2, 0, 0); stB(t2, 1, 0);
    BAR(); MMA(1, 0); BAR();
    stA(t2, 1, 0); stA(t2, 3, 0);
    VW6();
    BAR(); MMA(1, 1); BAR();
    LDA(0, 1); LDB(0, 1);
    if constexpr (BN == 256) { stB(t2, 2, 0); stB(t2, 3, 0); }
    BAR(); MMA(0, 0); BAR();
    LDB(1, 1);
    stA(t3, 0, 1); stA(t3, 2, 1);
    BAR(); MMA(0, 1); BAR();
    LDA(1, 1);
    stB(t3, 0, 1); stB(t3, 1, 1);
    BAR(); MMA(1, 0); BAR();
    stA(t3, 1, 1); stA(t3, 3, 1);
    VW6();
    BAR(); MMA(1, 1); BAR();
  }
  asm volatile("s_waitcnt vmcnt(0)" ::: "memory");
}

// ---------------- Fused QKV GEMM (256^2) ----------------
// XCD mapping: XCD (bid&7) owns bn-group of 4 x all 8 bm -> per-XCD L2
// working set 384 KB/K-step; B read once per 4-col group.
__global__ __launch_bounds__(512, 2)
void qkv_gemm8_kernel(const short* __restrict__ hsb, const short* __restrict__ Wt,
                      short* __restrict__ qb, short* __restrict__ kbuf,
                      short* __restrict__ vtb)
{
  int bid = blockIdx.x;
  int bm = bid >> 5;                                  // bits 5-7
  int bn = (bid & 7) * 4 + ((bid >> 3) & 3);          // XCD-grouped bn
  int m0 = bm * 256, n0 = bn * 256;
  int tid = threadIdx.x;
  int row8 = tid >> 3;
  int colsw = ((tid & 7) ^ (row8 & 7)) * 8;
  const short* srcA = hsb + (size_t)(m0 + row8) * HID + colsw;
  const short* srcB = Wt + (size_t)(n0 + row8) * HID + colsw;
  f32x4 acc[8][4] = {};
  gemm_ph<256, HID>(srcA, srcB, tid, HID / 64, acc);

  int wv = tid >> 6, lane = tid & 63;
  int lr = lane & 15, lk = lane >> 4;
  int wm = (wv >> 2) * 128, wn = (wv & 3) * 64;
  int region = (n0 < 4096) ? 0 : ((n0 < 6144) ? 1 : 2);
  #pragma unroll
  for (int m = 0; m < 8; ++m) {
    int srow_b = m0 + wm + m * 16 + lk * 4;
    #pragma unroll
    for (int n = 0; n < 4; ++n) {
      int ncol = n0 + wn + n * 16 + lr;
      #pragma unroll
      for (int r = 0; r < 4; ++r) {
        int srow = srow_b + r;
        short bv = f2bf(acc[m][n][r]);
        if (region == 0) {
          int h = ncol >> 8, d = ncol & 255;
          qb[((size_t)h * S + srow) * DH + d] = bv;
        } else if (region == 1) {
          int c = ncol - 4096; int kv = c >> 8, d = c & 255;
          kbuf[((size_t)kv * S + srow) * DH + d] = bv;
        } else {
          int c = ncol - 6144; int kv = c >> 8, d = c & 255;
          vtb[((size_t)kv * DH + d) * S + srow] = bv;
        }
      }
    }
  }
}

// ---------------- Output GEMM (256x128) ----------------
// XCD mapping: flat = xcd*28 + i; bn = flat>>3 (grouped 4-5/XCD), bm = flat&7.
__global__ __launch_bounds__(512, 2)
void out_gemm8_kernel(const short* __restrict__ attnb, const short* __restrict__ WtO,
                      float* __restrict__ out)
{
  int bid = blockIdx.x;
  int flat = (bid & 7) * 28 + (bid >> 3);
  int bn = flat >> 3, bm = flat & 7;
  int m0 = bm * 256, n0 = bn * 128;
  int tid = threadIdx.x;
  int row8 = tid >> 3;
  int colsw = ((tid & 7) ^ (row8 & 7)) * 8;
  const short* srcA = attnb + (size_t)(m0 + row8) * 4096 + colsw;
  const short* srcB = WtO + (size_t)(n0 + row8) * 4096 + colsw;
  f32x4 acc[8][2] = {};
  gemm_ph<128, 4096>(srcA, srcB, tid, 4096 / 64, acc);

  int wv = tid >> 6, lane = tid & 63;
  int lr = lane & 15, lk = lane >> 4;
  int wm = (wv >> 2) * 128, wn = (wv & 3) * 32;
  #pragma unroll
  for (int m = 0; m < 8; ++m) {
    int srow_b = m0 + wm + m * 16 + lk * 4;
    #pragma unroll
    for (int n = 0; n < 2; ++n) {
      int ncol = n0 + wn + n * 16 + lr;
      #pragma unroll
      for (int r = 0; r < 4; ++r)
        out[(size_t)(srow_b + r) * HID + ncol] = acc[m][n][r];
    }
  }
}

// ---------------- RoPE (NeoX, in place on q and k) ----------------
__global__ void rope_kernel(short* __restrict__ qb, short* __restrict__ kbuf,
                            const float2* __restrict__ tbl)
{
  int gid = blockIdx.x * 256 + threadIdx.x;
  int row = gid >> 4, ch = gid & 15;
  short* base = (row < NH * S) ? (qb + (size_t)row * DH)
                               : (kbuf + (size_t)(row - NH * S) * DH);
  int s = row & (S - 1);
  int i0 = ch * 8;
  s16x8 x1 = *(s16x8*)(base + i0);
  s16x8 x2 = *(s16x8*)(base + 128 + i0);
  s16x8 y1, y2;
  #pragma unroll
  for (int j = 0; j < 8; ++j) {
    float2 cs = tbl[s * 128 + i0 + j];
    float a = bf2f(x1[j]), b = bf2f(x2[j]);
    y1[j] = f2bf(a * cs.x - b * cs.y);
    y2[j] = f2bf(b * cs.x + a * cs.y);
  }
  *(s16x8*)(base + i0) = y1;
  *(s16x8*)(base + 128 + i0) = y2;
}

// ---------------- Attention v5: 8-wave two-group k-split (unchanged) ------
__global__ __launch_bounds__(512)
void attn_kernel(const short* __restrict__ qb, const short* __restrict__ kbuf,
                 const short* __restrict__ vtb, short* __restrict__ attnb)
{
  __shared__ __align__(16) short Klds[2][64][256];   // 64 KB
  __shared__ __align__(16) short Vlds[2][256][72];   // 73.7 KB
  __shared__ __align__(16) short Plds[8][16][72];    // 18.4 KB
  int bid = blockIdx.x;
  int qt = 31 - (bid >> 4), h = bid & 15;   // longest blocks first
  int kv = h >> 1;
  int q0 = qt * 64;
  int tid = threadIdx.x;
  int w = tid >> 6, lane = tid & 63;
  int g = w >> 2, wsub = w & 3;
  int gtid = tid & 255;
  int lr = lane & 15, lk = lane >> 4;
  int qrow_base = q0 + wsub * 16;
  s16x8 qf[8];
  const short* qrow = qb + ((size_t)h * S + (qrow_base + lr)) * DH;
  #pragma unroll
  for (int kb = 0; kb < 8; ++kb)
    qf[kb] = *(const s16x8*)(qrow + kb * 32 + lk * 8);
  f32x4 acc_o[16] = {};
  float l_r[4] = {0.0f, 0.0f, 0.0f, 0.0f};
  int tlo = (q0 >= WINDOW - 1) ? ((q0 - (WINDOW - 1)) >> 6) : 0;
  int thi = q0 >> 6;
  const short* kbase = kbuf + (size_t)kv * S * DH;
  const short* vbase = vtb + (size_t)kv * DH * S;

  s16x8 kpf[8], vpf[8];
  auto loadRegs = [&](int t) {
    int k0 = t * 64;
    #pragma unroll
    for (int it = 0; it < 8; ++it) {
      int flat = it * 256 + gtid;
      int r = flat >> 5, cg = flat & 31;
      kpf[it] = *(const s16x8*)(kbase + (size_t)(k0 + r) * DH + cg * 8);
    }
    #pragma unroll
    for (int it = 0; it < 8; ++it) {
      int flat = it * 256 + gtid;
      int r = flat >> 3, cg = flat & 7;
      vpf[it] = *(const s16x8*)(vbase + (size_t)r * S + k0 + cg * 8);
    }
  };
  auto writeLds = [&]() {
    #pragma unroll
    for (int it = 0; it < 8; ++it) {
      int flat = it * 256 + gtid;
      int r = flat >> 5, cg = flat & 31;
      *(s16x8*)&Klds[g][r][(cg ^ (r & 7)) * 8] = kpf[it];
    }
    #pragma unroll
    for (int it = 0; it < 8; ++it) {
      int flat = it * 256 + gtid;
      int r = flat >> 3, cg = flat & 7;
      *(s16x8*)&Vlds[g][r][(cg ^ (r & 7)) * 8] = vpf[it];
    }
  };

  int tg0 = tlo + g;
  int n_all = thi - tlo + 1;
  int jmax = (n_all + 1) >> 1;
  if (tg0 <= thi) loadRegs(tg0);
  for (int j = 0; j < jmax; ++j) {
    int t = tg0 + 2 * j;
    bool active = (t <= thi);
    if (active) writeLds();
    __syncthreads();
    if (active && t + 2 <= thi) loadRegs(t + 2);
    if (active) {
      int k0 = t * 64;
      f32x4 sc4[4] = {};
      __builtin_amdgcn_s_setprio(1);
      #pragma unroll
      for (int kb = 0; kb < 8; ++kb)
        #pragma unroll
        for (int ni = 0; ni < 4; ++ni) {
          int row = ni * 16 + lr;
          s16x8 b = *(const s16x8*)&Klds[g][row][(((kb << 2) | lk) ^ (row & 7)) * 8];
          sc4[ni] = __builtin_amdgcn_mfma_f32_16x16x32_bf16(qf[kb], b, sc4[ni], 0, 0, 0);
        }
      __builtin_amdgcn_s_setprio(0);
      bool interior = (k0 + 63 <= qrow_base) && (qrow_base + 15 - k0 < WINDOW);
      #pragma unroll
      for (int ni = 0; ni < 4; ++ni)
        #pragma unroll
        for (int r = 0; r < 4; ++r) {
          float raw = sc4[ni][r];
          float u = fabsf(raw) * (2.0f * SCALE / CAP);
          float e = __expf(-u);
          float th = (1.0f - e) / (1.0f + e);
          float z = CAP * copysignf(th, raw) - CAP;
          if (!interior) {
            int qg = qrow_base + lk * 4 + r;
            int kg = k0 + ni * 16 + lr;
            bool valid = (kg <= qg) && (qg - kg < WINDOW);
            z = valid ? z : -1e30f;
          }
          float p = __expf(z);
          sc4[ni][r] = p;
          l_r[r] += p;
        }
      #pragma unroll
      for (int ni = 0; ni < 4; ++ni)
        #pragma unroll
        for (int r = 0; r < 4; ++r)
          Plds[w][lk * 4 + r][ni * 16 + lr] = f2bf(sc4[ni][r]);
      s16x8 pa0 = *(const s16x8*)&Plds[w][lr][lk * 8];
      s16x8 pa1 = *(const s16x8*)&Plds[w][lr][32 + lk * 8];
      __builtin_amdgcn_s_setprio(1);
      #pragma unroll
      for (int df = 0; df < 16; ++df) {
        int row = df * 16 + lr;
        s16x8 b0 = *(const s16x8*)&Vlds[g][row][((lk ^ (row & 7)) * 8)];
        s16x8 b1 = *(const s16x8*)&Vlds[g][row][(((4 + lk) ^ (row & 7)) * 8)];
        acc_o[df] = __builtin_amdgcn_mfma_f32_16x16x32_bf16(pa0, b0, acc_o[df], 0, 0, 0);
        acc_o[df] = __builtin_amdgcn_mfma_f32_16x16x32_bf16(pa1, b1, acc_o[df], 0, 0, 0);
      }
      __builtin_amdgcn_s_setprio(0);
    }
    __syncthreads();
  }
  float lsum[4];
  #pragma unroll
  for (int r = 0; r < 4; ++r) {
    float v = l_r[r];
    #pragma unroll
    for (int off = 1; off < 16; off <<= 1)
      v += __shfl_xor(v, off, 64);
    lsum[r] = v;
  }
  float* comb = (float*)&Klds[0][0][0];   // [64][256] f32
  float* lcomb = (float*)&Vlds[0][0][0];  // [64] f32
  if (g == 1) {
    #pragma unroll
    for (int df = 0; df < 16; ++df)
      #pragma unroll
      for (int r = 0; r < 4; ++r)
        comb[(size_t)(wsub * 16 + lk * 4 + r) * 256 + df * 16 + lr] = acc_o[df][r];
    if (lr == 0)
      #pragma unroll
      for (int r = 0; r < 4; ++r)
        lcomb[wsub * 16 + lk * 4 + r] = lsum[r];
  }
  __syncthreads();
  if (g == 0) {
    #pragma unroll
    for (int r = 0; r < 4; ++r) {
      int rowi = wsub * 16 + lk * 4 + r;
      float lt = lsum[r] + lcomb[rowi];
      float inv = 1.0f / lt;
      int srow = q0 + rowi;
      #pragma unroll
      for (int df = 0; df < 16; ++df) {
        float o = acc_o[df][r] + comb[(size_t)rowi * 256 + df * 16 + lr];
        attnb[(size_t)srow * (NH * DH) + h * DH + df * 16 + lr] = f2bf(o * inv);
      }
    }
  }
}

extern "C" void kernel_launch(void* const* d_in, const int* in_sizes, int n_in,
                              void* d_out, int out_size, void* d_ws, size_t ws_size,
                              hipStream_t stream) {
  const float* hs = (const float*)d_in[0];
  const float* Wq = (const float*)d_in[2];
  const float* Wk = (const float*)d_in[3];
  const float* Wv = (const float*)d_in[4];
  const float* Wo = (const float*)d_in[5];
  float* out = (float*)d_out;
  char* ws = (char*)d_ws;
  size_t off = 0;
  float2* tbl  = (float2*)(ws + off); off += 2097152;
  short* qb    = (short*)(ws + off);  off += 16777216;           // q  [H][S][D]
  short* kbuf  = (short*)(ws + off);  off += 8388608;            // k  [KV][S][D]
  short* vtb   = (short*)(ws + off);  off += 8388608;            // vT [KV][D][S]
  short* attnb = (short*)(ws + off);  off += 16777216;           // attn [S][4096]
  short* hsb   = (short*)(ws + off);  off += 14680064;           // hs bf16
  short* Wt    = (short*)(ws + off);  off += 58720256;           // [8192][3584]
  short* WtO   = (short*)(ws + off);  off += 29360128;           // [3584][4096]

  hipLaunchKernelGGL(rope_table_kernel, dim3(1024), dim3(256), 0, stream, tbl);
  hipLaunchKernelGGL(conv_hs_kernel, dim3(3584), dim3(256), 0, stream, hs, hsb);
  hipLaunchKernelGGL(transpose_kernel, dim3(64 * 56), dim3(256), 0, stream,
                     Wq, Wt, HID, 4096);
  hipLaunchKernelGGL(transpose_kernel, dim3(32 * 56), dim3(256), 0, stream,
                     Wk, Wt + (size_t)4096 * HID, HID, 2048);
  hipLaunchKernelGGL(transpose_kernel, dim3(32 * 56), dim3(256), 0, stream,
                     Wv, Wt + (size_t)6144 * HID, HID, 2048);
  hipLaunchKernelGGL(transpose_kernel, dim3(56 * 64), dim3(256), 0, stream,
                     Wo, WtO, 4096, HID);
  hipLaunchKernelGGL(qkv_gemm8_kernel, dim3(256), dim3(512), 0, stream,
                     hsb, Wt, qb, kbuf, vtb);
  hipLaunchKernelGGL(rope_kernel, dim3(3072), dim3(256), 0, stream, qb, kbuf, tbl);
  hipLaunchKernelGGL(attn_kernel, dim3(512), dim3(512), 0, stream,
                     qb, kbuf, vtb, attnb);
  hipLaunchKernelGGL(out_gemm8_kernel, dim3(224), dim3(512), 0, stream,
                     attnb, WtO, out);
}

// Round 12
// 377.578 us; speedup vs baseline: 1.1080x; 1.0452x over previous
//
#include <hip/hip_runtime.h>
#include <stdint.h>

#define S 2048
#define HID 3584
#define NH 16
#define NKV 8
#define DH 256
#define WINDOW 1024
#define SCALE 0.0625f
#define CAP 50.0f

typedef short s16x8 __attribute__((ext_vector_type(8)));
typedef float f32x4 __attribute__((ext_vector_type(4)));

__device__ __forceinline__ short f2bf(float f) {
  union { float f; uint32_t u; } c; c.f = f;
  uint32_t u = c.u;
  uint32_t r = (u + 0x7FFFu + ((u >> 16) & 1u)) >> 16;
  return (short)r;
}
__device__ __forceinline__ float bf2f(short s) {
  union { uint32_t u; float f; } c;
  c.u = ((uint32_t)(uint16_t)s) << 16;
  return c.f;
}
__device__ __forceinline__ void gll16(const void* g, void* l) {
  __builtin_amdgcn_global_load_lds((const __attribute__((address_space(1))) void*)g,
                                   (__attribute__((address_space(3))) void*)l, 16, 0, 0);
}

// ---------------- RoPE table ----------------
__global__ void rope_table_kernel(float2* __restrict__ tbl) {
  int idx = blockIdx.x * 256 + threadIdx.x;
  int s = idx >> 7, i = idx & 127;
  float inv = __expf(-(float)i * (9.210340371976184f / 128.0f));
  float fr = (float)s * inv;
  tbl[idx] = make_float2(cosf(fr), sinf(fr));
}

// ---------------- hs fp32 -> bf16 ----------------
__global__ void conv_hs_kernel(const float* __restrict__ src, short* __restrict__ dst) {
  int gid = blockIdx.x * 256 + threadIdx.x;
  float4 a = *(const float4*)&src[(size_t)gid * 8];
  float4 b = *(const float4*)&src[(size_t)gid * 8 + 4];
  s16x8 o;
  o[0] = f2bf(a.x); o[1] = f2bf(a.y); o[2] = f2bf(a.z); o[3] = f2bf(a.w);
  o[4] = f2bf(b.x); o[5] = f2bf(b.y); o[6] = f2bf(b.z); o[7] = f2bf(b.w);
  *(s16x8*)&dst[(size_t)gid * 8] = o;
}

// ------- All W transposes fused: fp32 [K][N] -> bf16 [N][K] -------
__global__ __launch_bounds__(256)
void transpose_all_kernel(const float* __restrict__ Wq, const float* __restrict__ Wk,
                          const float* __restrict__ Wv, const float* __restrict__ Wo,
                          short* __restrict__ Wt, short* __restrict__ WtO)
{
  __shared__ __align__(16) short t[64][76];
  int b = blockIdx.x;
  const float* src; short* dst; int K, N, lb;
  if (b < 3584)      { src = Wq; dst = Wt;                       K = HID;  N = 4096; lb = b; }
  else if (b < 5376) { src = Wk; dst = Wt + (size_t)4096 * HID;  K = HID;  N = 2048; lb = b - 3584; }
  else if (b < 7168) { src = Wv; dst = Wt + (size_t)6144 * HID;  K = HID;  N = 2048; lb = b - 5376; }
  else               { src = Wo; dst = WtO;                      K = 4096; N = HID;  lb = b - 7168; }
  int ntn = N >> 6;
  int tn = lb % ntn, tk = lb / ntn;
  int tid = threadIdx.x;
  int c = tid & 63, rg = tid >> 6;
  #pragma unroll
  for (int i = 0; i < 4; ++i) {
    int r0 = i * 16 + rg * 4;
    short tmp[4];
    #pragma unroll
    for (int j = 0; j < 4; ++j)
      tmp[j] = f2bf(src[(size_t)(tk * 64 + r0 + j) * N + tn * 64 + c]);
    *(short4*)&t[c][r0] = *(short4*)tmp;
  }
  __syncthreads();
  #pragma unroll
  for (int it = 0; it < 2; ++it) {
    int flat = it * 256 + tid;
    int n = flat >> 3, kc = flat & 7;
    *(s16x8*)&dst[(size_t)(tn * 64 + n) * K + tk * 64 + kc * 8] = *(s16x8*)&t[n][kc * 8];
  }
}

// ====== m97-style single-buffer GEMM, 256x128 tile, BK=64, 256 thr ========
// 2 blocks/CU co-resident: one block's compute fills the other's stage/sync
// stalls (m114 mechanism). XOR-swizzle chunk ^= row&7 both sides.
__global__ __launch_bounds__(256, 2)
void qkv_gemm_kernel(const short* __restrict__ hsb, const short* __restrict__ Wt,
                     short* __restrict__ qb, short* __restrict__ kbuf,
                     short* __restrict__ vtb)
{
  __shared__ __align__(16) short Asb[256 * 64];   // 32 KB
  __shared__ __align__(16) short Bsb[128 * 64];   // 16 KB
  int bid = blockIdx.x;                            // 512 = 8 xcd x (8 bm x 8 bn)
  int i = bid >> 3;
  int bm = i & 7;
  int bn = (bid & 7) * 8 + (i >> 3);
  int m0 = bm * 256, n0 = bn * 128;
  int tid = threadIdx.x, w = tid >> 6, lane = tid & 63;
  int lr = lane & 15, lk = lane >> 4;
  int wm = (w >> 1) * 128, wn = (w & 1) * 64;
  int r7 = lr & 7;
  int abase = (wm + lr) * 64 + ((lk ^ r7) * 8);
  int bbase = (wn + lr) * 64 + ((lk ^ r7) * 8);
  int row8 = tid >> 3;                             // 0..31
  int colsw = ((tid & 7) ^ (row8 & 7)) * 8;
  const short* srcA = hsb + (size_t)(m0 + row8) * HID + colsw;
  const short* srcB = Wt + (size_t)(n0 + row8) * HID + colsw;
  f32x4 acc[8][4] = {};
  for (int t = 0; t < HID / 64; ++t) {
    const short* sa = srcA + t * 64;
    const short* sb = srcB + t * 64;
    #pragma unroll
    for (int r = 0; r < 8; ++r)
      gll16(sa + (size_t)(r * 32) * HID, Asb + r * 2048 + w * 512);
    #pragma unroll
    for (int r = 0; r < 4; ++r)
      gll16(sb + (size_t)(r * 32) * HID, Bsb + r * 2048 + w * 512);
    __syncthreads();                               // drains vmcnt -> data ready
    s16x8 bf[4][2];
    #pragma unroll
    for (int nf = 0; nf < 4; ++nf)
      #pragma unroll
      for (int kh = 0; kh < 2; ++kh)
        bf[nf][kh] = *(const s16x8*)&Bsb[(bbase + nf * 16 * 64) ^ (kh * 32)];
    #pragma unroll
    for (int mh = 0; mh < 2; ++mh) {
      s16x8 af[4][2];
      #pragma unroll
      for (int mf = 0; mf < 4; ++mf)
        #pragma unroll
        for (int kh = 0; kh < 2; ++kh)
          af[mf][kh] = *(const s16x8*)&Asb[(abase + (mh * 64 + mf * 16) * 64) ^ (kh * 32)];
      __builtin_amdgcn_s_setprio(1);
      #pragma unroll
      for (int mf = 0; mf < 4; ++mf)
        #pragma unroll
        for (int nf = 0; nf < 4; ++nf) {
          acc[mh * 4 + mf][nf] = __builtin_amdgcn_mfma_f32_16x16x32_bf16(
              af[mf][0], bf[nf][0], acc[mh * 4 + mf][nf], 0, 0, 0);
          acc[mh * 4 + mf][nf] = __builtin_amdgcn_mfma_f32_16x16x32_bf16(
              af[mf][1], bf[nf][1], acc[mh * 4 + mf][nf], 0, 0, 0);
        }
      __builtin_amdgcn_s_setprio(0);
    }
    __syncthreads();                               // all reads done before next stage
  }
  int region = (n0 < 4096) ? 0 : ((n0 < 6144) ? 1 : 2);
  #pragma unroll
  for (int m = 0; m < 8; ++m) {
    int srow_b = m0 + wm + m * 16 + lk * 4;
    #pragma unroll
    for (int n = 0; n < 4; ++n) {
      int ncol = n0 + wn + n * 16 + lr;
      #pragma unroll
      for (int r = 0; r < 4; ++r) {
        int srow = srow_b + r;
        short bv = f2bf(acc[m][n][r]);
        if (region == 0) {
          int h = ncol >> 8, d = ncol & 255;
          qb[((size_t)h * S + srow) * DH + d] = bv;
        } else if (region == 1) {
          int c = ncol - 4096; int kv = c >> 8, d = c & 255;
          kbuf[((size_t)kv * S + srow) * DH + d] = bv;
        } else {
          int c = ncol - 6144; int kv = c >> 8, d = c & 255;
          vtb[((size_t)kv * DH + d) * S + srow] = bv;
        }
      }
    }
  }
}

// ====== Output GEMM: m97-classic 128x128, BK=64, 256 thr, 3 blocks/CU =====
__global__ __launch_bounds__(256)
void out_gemm_kernel(const short* __restrict__ attnb, const short* __restrict__ WtO,
                     float* __restrict__ out)
{
  __shared__ __align__(16) short Asb[128 * 64];   // 16 KB
  __shared__ __align__(16) short Bsb[128 * 64];   // 16 KB
  int bid = blockIdx.x;                            // 448 = 16 bm x 28 bn
  int flat = (bid & 7) * 56 + (bid >> 3);
  int bn = flat >> 4, bm = flat & 15;
  int m0 = bm * 128, n0 = bn * 128;
  int tid = threadIdx.x, w = tid >> 6, lane = tid & 63;
  int lr = lane & 15, lk = lane >> 4;
  int wm = (w >> 1) * 64, wn = (w & 1) * 64;
  int r7 = lr & 7;
  int abase = (wm + lr) * 64 + ((lk ^ r7) * 8);
  int bbase = (wn + lr) * 64 + ((lk ^ r7) * 8);
  int row8 = tid >> 3;
  int colsw = ((tid & 7) ^ (row8 & 7)) * 8;
  const short* srcA = attnb + (size_t)(m0 + row8) * 4096 + colsw;
  const short* srcB = WtO + (size_t)(n0 + row8) * 4096 + colsw;
  f32x4 acc[4][4] = {};
  for (int t = 0; t < 4096 / 64; ++t) {
    const short* sa = srcA + t * 64;
    const short* sb = srcB + t * 64;
    #pragma unroll
    for (int r = 0; r < 4; ++r)
      gll16(sa + (size_t)(r * 32) * 4096, Asb + r * 2048 + w * 512);
    #pragma unroll
    for (int r = 0; r < 4; ++r)
      gll16(sb + (size_t)(r * 32) * 4096, Bsb + r * 2048 + w * 512);
    __syncthreads();
    s16x8 af[4][2], bf[4][2];
    #pragma unroll
    for (int f = 0; f < 4; ++f)
      #pragma unroll
      for (int kh = 0; kh < 2; ++kh) {
        af[f][kh] = *(const s16x8*)&Asb[(abase + f * 16 * 64) ^ (kh * 32)];
        bf[f][kh] = *(const s16x8*)&Bsb[(bbase + f * 16 * 64) ^ (kh * 32)];
      }
    __builtin_amdgcn_s_setprio(1);
    #pragma unroll
    for (int mf = 0; mf < 4; ++mf)
      #pragma unroll
      for (int nf = 0; nf < 4; ++nf) {
        acc[mf][nf] = __builtin_amdgcn_mfma_f32_16x16x32_bf16(
            af[mf][0], bf[nf][0], acc[mf][nf], 0, 0, 0);
        acc[mf][nf] = __builtin_amdgcn_mfma_f32_16x16x32_bf16(
            af[mf][1], bf[nf][1], acc[mf][nf], 0, 0, 0);
      }
    __builtin_amdgcn_s_setprio(0);
    __syncthreads();
  }
  #pragma unroll
  for (int mf = 0; mf < 4; ++mf) {
    int srow_b = m0 + wm + mf * 16 + lk * 4;
    #pragma unroll
    for (int nf = 0; nf < 4; ++nf) {
      int ncol = n0 + wn + nf * 16 + lr;
      #pragma unroll
      for (int r = 0; r < 4; ++r)
        out[(size_t)(srow_b + r) * HID + ncol] = acc[mf][nf][r];
    }
  }
}

// ---------------- RoPE (NeoX, in place on q and k) ----------------
__global__ void rope_kernel(short* __restrict__ qb, short* __restrict__ kbuf,
                            const float2* __restrict__ tbl)
{
  int gid = blockIdx.x * 256 + threadIdx.x;
  int row = gid >> 4, ch = gid & 15;
  short* base = (row < NH * S) ? (qb + (size_t)row * DH)
                               : (kbuf + (size_t)(row - NH * S) * DH);
  int s = row & (S - 1);
  int i0 = ch * 8;
  s16x8 x1 = *(s16x8*)(base + i0);
  s16x8 x2 = *(s16x8*)(base + 128 + i0);
  s16x8 y1, y2;
  #pragma unroll
  for (int j = 0; j < 8; ++j) {
    float2 cs = tbl[s * 128 + i0 + j];
    float a = bf2f(x1[j]), b = bf2f(x2[j]);
    y1[j] = f2bf(a * cs.x - b * cs.y);
    y2[j] = f2bf(b * cs.x + a * cs.y);
  }
  *(s16x8*)(base + i0) = y1;
  *(s16x8*)(base + 128 + i0) = y2;
}

// ---------------- Attention v5.1: 8-wave two-group k-split ----------------
// Merged-exp softcap: p = exp(-2*CAP*w/(1+e)), w = (raw>0 ? e : 1),
// e = exp(-2|s|/CAP). Vlds stride 64 (swizzle handles banks).
__global__ __launch_bounds__(512)
void attn_kernel(const short* __restrict__ qb, const short* __restrict__ kbuf,
                 const short* __restrict__ vtb, short* __restrict__ attnb)
{
  __shared__ __align__(16) short Klds[2][64][256];   // 64 KB
  __shared__ __align__(16) short Vlds[2][256][64];   // 64 KB
  __shared__ __align__(16) short Plds[8][16][72];    // 18.4 KB
  int bid = blockIdx.x;
  int qt = 31 - (bid >> 4), h = bid & 15;
  int kv = h >> 1;
  int q0 = qt * 64;
  int tid = threadIdx.x;
  int w = tid >> 6, lane = tid & 63;
  int g = w >> 2, wsub = w & 3;
  int gtid = tid & 255;
  int lr = lane & 15, lk = lane >> 4;
  int qrow_base = q0 + wsub * 16;
  s16x8 qf[8];
  const short* qrow = qb + ((size_t)h * S + (qrow_base + lr)) * DH;
  #pragma unroll
  for (int kb = 0; kb < 8; ++kb)
    qf[kb] = *(const s16x8*)(qrow + kb * 32 + lk * 8);
  f32x4 acc_o[16] = {};
  float l_r[4] = {0.0f, 0.0f, 0.0f, 0.0f};
  int tlo = (q0 >= WINDOW - 1) ? ((q0 - (WINDOW - 1)) >> 6) : 0;
  int thi = q0 >> 6;
  const short* kbase = kbuf + (size_t)kv * S * DH;
  const short* vbase = vtb + (size_t)kv * DH * S;

  s16x8 kpf[8], vpf[8];
  auto loadRegs = [&](int t) {
    int k0 = t * 64;
    #pragma unroll
    for (int it = 0; it < 8; ++it) {
      int flat = it * 256 + gtid;
      int r = flat >> 5, cg = flat & 31;
      kpf[it] = *(const s16x8*)(kbase + (size_t)(k0 + r) * DH + cg * 8);
    }
    #pragma unroll
    for (int it = 0; it < 8; ++it) {
      int flat = it * 256 + gtid;
      int r = flat >> 3, cg = flat & 7;
      vpf[it] = *(const s16x8*)(vbase + (size_t)r * S + k0 + cg * 8);
    }
  };
  auto writeLds = [&]() {
    #pragma unroll
    for (int it = 0; it < 8; ++it) {
      int flat = it * 256 + gtid;
      int r = flat >> 5, cg = flat & 31;
      *(s16x8*)&Klds[g][r][(cg ^ (r & 7)) * 8] = kpf[it];
    }
    #pragma unroll
    for (int it = 0; it < 8; ++it) {
      int flat = it * 256 + gtid;
      int r = flat >> 3, cg = flat & 7;
      *(s16x8*)&Vlds[g][r][(cg ^ (r & 7)) * 8] = vpf[it];
    }
  };

  int tg0 = tlo + g;
  int n_all = thi - tlo + 1;
  int jmax = (n_all + 1) >> 1;
  if (tg0 <= thi) loadRegs(tg0);
  for (int j = 0; j < jmax; ++j) {
    int t = tg0 + 2 * j;
    bool active = (t <= thi);
    if (active) writeLds();
    __syncthreads();
    if (active && t + 2 <= thi) loadRegs(t + 2);
    if (active) {
      int k0 = t * 64;
      f32x4 sc4[4] = {};
      __builtin_amdgcn_s_setprio(1);
      #pragma unroll
      for (int kb = 0; kb < 8; ++kb)
        #pragma unroll
        for (int ni = 0; ni < 4; ++ni) {
          int row = ni * 16 + lr;
          s16x8 b = *(const s16x8*)&Klds[g][row][(((kb << 2) | lk) ^ (row & 7)) * 8];
          sc4[ni] = __builtin_amdgcn_mfma_f32_16x16x32_bf16(qf[kb], b, sc4[ni], 0, 0, 0);
        }
      __builtin_amdgcn_s_setprio(0);
      bool interior = (k0 + 63 <= qrow_base) && (qrow_base + 15 - k0 < WINDOW);
      #pragma unroll
      for (int ni = 0; ni < 4; ++ni)
        #pragma unroll
        for (int r = 0; r < 4; ++r) {
          float raw = sc4[ni][r];
          float e = __expf(-fabsf(raw) * (2.0f * SCALE / CAP));
          float wgt = raw > 0.0f ? e : 1.0f;
          float p = __expf(-2.0f * CAP * __fdividef(wgt, 1.0f + e));
          if (!interior) {
            int qg = qrow_base + lk * 4 + r;
            int kg = k0 + ni * 16 + lr;
            bool valid = (kg <= qg) && (qg - kg < WINDOW);
            p = valid ? p : 0.0f;
          }
          sc4[ni][r] = p;
          l_r[r] += p;
        }
      #pragma unroll
      for (int ni = 0; ni < 4; ++ni)
        #pragma unroll
        for (int r = 0; r < 4; ++r)
          Plds[w][lk * 4 + r][ni * 16 + lr] = f2bf(sc4[ni][r]);
      s16x8 pa0 = *(const s16x8*)&Plds[w][lr][lk * 8];
      s16x8 pa1 = *(const s16x8*)&Plds[w][lr][32 + lk * 8];
      __builtin_amdgcn_s_setprio(1);
      #pragma unroll
      for (int df = 0; df < 16; ++df) {
        int row = df * 16 + lr;
        s16x8 b0 = *(const s16x8*)&Vlds[g][row][((lk ^ (row & 7)) * 8)];
        s16x8 b1 = *(const s16x8*)&Vlds[g][row][(((4 + lk) ^ (row & 7)) * 8)];
        acc_o[df] = __builtin_amdgcn_mfma_f32_16x16x32_bf16(pa0, b0, acc_o[df], 0, 0, 0);
        acc_o[df] = __builtin_amdgcn_mfma_f32_16x16x32_bf16(pa1, b1, acc_o[df], 0, 0, 0);
      }
      __builtin_amdgcn_s_setprio(0);
    }
    __syncthreads();
  }
  float lsum[4];
  #pragma unroll
  for (int r = 0; r < 4; ++r) {
    float v = l_r[r];
    #pragma unroll
    for (int off = 1; off < 16; off <<= 1)
      v += __shfl_xor(v, off, 64);
    lsum[r] = v;
  }
  float* comb = (float*)&Klds[0][0][0];   // [64][256] f32
  float* lcomb = (float*)&Vlds[0][0][0];  // [64] f32
  if (g == 1) {
    #pragma unroll
    for (int df = 0; df < 16; ++df)
      #pragma unroll
      for (int r = 0; r < 4; ++r)
        comb[(size_t)(wsub * 16 + lk * 4 + r) * 256 + df * 16 + lr] = acc_o[df][r];
    if (lr == 0)
      #pragma unroll
      for (int r = 0; r < 4; ++r)
        lcomb[wsub * 16 + lk * 4 + r] = lsum[r];
  }
  __syncthreads();
  if (g == 0) {
    #pragma unroll
    for (int r = 0; r < 4; ++r) {
      int rowi = wsub * 16 + lk * 4 + r;
      float lt = lsum[r] + lcomb[rowi];
      float inv = 1.0f / lt;
      int srow = q0 + rowi;
      #pragma unroll
      for (int df = 0; df < 16; ++df) {
        float o = acc_o[df][r] + comb[(size_t)rowi * 256 + df * 16 + lr];
        attnb[(size_t)srow * (NH * DH) + h * DH + df * 16 + lr] = f2bf(o * inv);
      }
    }
  }
}

extern "C" void kernel_launch(void* const* d_in, const int* in_sizes, int n_in,
                              void* d_out, int out_size, void* d_ws, size_t ws_size,
                              hipStream_t stream) {
  const float* hs = (const float*)d_in[0];
  const float* Wq = (const float*)d_in[2];
  const float* Wk = (const float*)d_in[3];
  const float* Wv = (const float*)d_in[4];
  const float* Wo = (const float*)d_in[5];
  float* out = (float*)d_out;
  char* ws = (char*)d_ws;
  size_t off = 0;
  float2* tbl  = (float2*)(ws + off); off += 2097152;
  short* qb    = (short*)(ws + off);  off += 16777216;           // q  [H][S][D]
  short* kbuf  = (short*)(ws + off);  off += 8388608;            // k  [KV][S][D]
  short* vtb   = (short*)(ws + off);  off += 8388608;            // vT [KV][D][S]
  short* attnb = (short*)(ws + off);  off += 16777216;           // attn [S][4096]
  short* hsb   = (short*)(ws + off);  off += 14680064;           // hs bf16
  short* Wt    = (short*)(ws + off);  off += 58720256;           // [8192][3584]
  short* WtO   = (short*)(ws + off);  off += 29360128;           // [3584][4096]

  hipLaunchKernelGGL(rope_table_kernel, dim3(1024), dim3(256), 0, stream, tbl);
  hipLaunchKernelGGL(conv_hs_kernel, dim3(3584), dim3(256), 0, stream, hs, hsb);
  hipLaunchKernelGGL(transpose_all_kernel, dim3(10752), dim3(256), 0, stream,
                     Wq, Wk, Wv, Wo, Wt, WtO);
  hipLaunchKernelGGL(qkv_gemm_kernel, dim3(512), dim3(256), 0, stream,
                     hsb, Wt, qb, kbuf, vtb);
  hipLaunchKernelGGL(rope_kernel, dim3(3072), dim3(256), 0, stream, qb, kbuf, tbl);
  hipLaunchKernelGGL(attn_kernel, dim3(512), dim3(512), 0, stream,
                     qb, kbuf, vtb, attnb);
  hipLaunchKernelGGL(out_gemm_kernel, dim3(448), dim3(256), 0, stream,
                     attnb, WtO, out);
}